// Round 7
// baseline (305.164 us; speedup 1.0000x reference)
//
#include <hip/hip_runtime.h>

#define LSEQ 200
#define KCAP 4
#define NVOC 100000

// ---------------------------------------------------------------------------
// Kernel 1: P = (E with row 0 zeroed) @ S, P: (NVOC, 64) in workspace.
// Verbatim round-6 version (passed; ~13 us). 64x64 tile, 4x4 per-thread.
// ---------------------------------------------------------------------------
__global__ __launch_bounds__(256) void precompute_P(
    const float* __restrict__ E, const float* __restrict__ S,
    float* __restrict__ P)
{
    __shared__ __align__(16) float Sl[64 * 64];   // Sl[e*64 + d]
    __shared__ __align__(16) float Et[64 * 68];   // Et[e*68 + r] = E[(vbase+r)*64+e]
    const int tid   = threadIdx.x;
    const int vbase = blockIdx.x * 64;

    #pragma unroll
    for (int t = tid; t < 4096; t += 256) Sl[t] = S[t];
    #pragma unroll
    for (int t = tid; t < 4096; t += 256) {
        int r = t >> 6, e = t & 63;               // wave: r fixed, e=lane -> coalesced
        int v = vbase + r;
        Et[e * 68 + r] = (v < NVOC) ? E[v * 64 + e] : 0.f;
    }
    __syncthreads();

    const int rq = tid >> 4;                      // 16 row-quads
    const int cq = tid & 15;                      // 16 col-quads
    float a00=0,a01=0,a02=0,a03=0, a10=0,a11=0,a12=0,a13=0;
    float a20=0,a21=0,a22=0,a23=0, a30=0,a31=0,a32=0,a33=0;
    #pragma unroll 8
    for (int e = 0; e < 64; e++) {
        float4 ev = *(const float4*)(Et + e * 68 + rq * 4);
        float4 sv = *(const float4*)(Sl + e * 64 + cq * 4);
        a00 = fmaf(ev.x, sv.x, a00); a01 = fmaf(ev.x, sv.y, a01);
        a02 = fmaf(ev.x, sv.z, a02); a03 = fmaf(ev.x, sv.w, a03);
        a10 = fmaf(ev.y, sv.x, a10); a11 = fmaf(ev.y, sv.y, a11);
        a12 = fmaf(ev.y, sv.z, a12); a13 = fmaf(ev.y, sv.w, a13);
        a20 = fmaf(ev.z, sv.x, a20); a21 = fmaf(ev.z, sv.y, a21);
        a22 = fmaf(ev.z, sv.z, a22); a23 = fmaf(ev.z, sv.w, a23);
        a30 = fmaf(ev.w, sv.x, a30); a31 = fmaf(ev.w, sv.y, a31);
        a32 = fmaf(ev.w, sv.z, a32); a33 = fmaf(ev.w, sv.w, a33);
    }

    const int r0 = vbase + rq * 4;
    float4 o0 = make_float4(a00, a01, a02, a03);
    float4 o1 = make_float4(a10, a11, a12, a13);
    float4 o2 = make_float4(a20, a21, a22, a23);
    float4 o3 = make_float4(a30, a31, a32, a33);
    if (r0 == 0) o0 = make_float4(0.f, 0.f, 0.f, 0.f);  // padding_idx=0
    if (r0 + 0 < NVOC) *(float4*)(P + (r0 + 0) * 64 + cq * 4) = o0;
    if (r0 + 1 < NVOC) *(float4*)(P + (r0 + 1) * 64 + cq * 4) = o1;
    if (r0 + 2 < NVOC) *(float4*)(P + (r0 + 2) * 64 + cq * 4) = o2;
    if (r0 + 3 < NVOC) *(float4*)(P + (r0 + 3) * 64 + cq * 4) = o3;
}

// ---------------------------------------------------------------------------
// Kernel 2: one batch row per block (256 threads = 4 waves).
// Arithmetic VERBATIM from passing rounds 5/6 (absmax 4.88e-4).
// ONE change: __launch_bounds__(256,4) -> (256,8). Counters across rounds
// show the 2nd arg caps residency (occ 22/47/40% at args 2/5/4); resources
// allow 8 blocks/CU (LDS 8*17408=139KB<160KB, VGPR 56<=64). Doubles the
// latency-hiding pool; no arithmetic change.
// Spill canaries: VGPR_Count < 56, or WRITE_SIZE >> 4 MB.
// ---------------------------------------------------------------------------
__global__ __launch_bounds__(256, 8) void mind_row(
    const int*   __restrict__ his, const float* __restrict__ P,
    const float* __restrict__ B0,  const float* __restrict__ W1,
    const float* __restrict__ b1,  const float* __restrict__ W2,
    const float* __restrict__ b2,  float* __restrict__ out)
{
    __shared__ __align__(16) float POOL[4336];
    float* Bm     = POOL;          // [k*208 + l]
    float* W4     = POOL + 832;    // [l*4 + k]
    float* caps4  = POOL + 1632;   // [d*4 + k]
    float* bigneg = POOL + 1888;   // [200]
    int*   idxs   = (int*)(POOL + 2088);   // [200], live whole kernel
    float* SC     = POOL + 2288;   // 2048-float union
    float* part   = SC;            // [q*256 + k*64 + d]  (phase B -> C; MLP2)
    float* h4     = SC + 1024;     // [f*4 + k]           (MLP)

    const int b    = blockIdx.x;
    const int tid  = threadIdx.x;
    const int lane = tid & 63;
    const int wv   = tid >> 6;

    // ---- setup -------------------------------------------------------------
    for (int l = tid; l < LSEQ; l += 256) {
        int id = his[b * LSEQ + l];
        idxs[l]   = id;
        bigneg[l] = (id != 0) ? 0.f : -1e30f;
    }
    if (tid < LSEQ) {
        #pragma unroll
        for (int k = 0; k < KCAP; k++) Bm[k * 208 + tid] = B0[k * LSEQ + tid];
    }
    __syncthreads();

    // ---- gather hisP rows: wave covers l in [wv*50, wv*50+50), lane = d ----
    float hp[50];
    #pragma unroll
    for (int i = 0; i < 50; i++) {
        int l = wv * 50 + i;
        hp[i] = P[idxs[l] * 64 + lane];     // 256B coalesced per wave; row0=0
    }

    for (int r = 0; r < 3; r++) {
        // A: masked softmax over l, capsule k = wv (one wave per capsule)
        {
            const float* Bk = Bm + wv * 208;
            float x0 = Bk[lane]       + bigneg[lane];
            float x1 = Bk[lane + 64]  + bigneg[lane + 64];
            float x2 = Bk[lane + 128] + bigneg[lane + 128];
            float x3 = (lane < 8) ? (Bk[lane + 192] + bigneg[lane + 192]) : -3.0e38f;
            float m = fmaxf(fmaxf(x0, x1), fmaxf(x2, x3));
            #pragma unroll
            for (int off = 32; off; off >>= 1) m = fmaxf(m, __shfl_xor(m, off, 64));
            float e0 = __expf(x0 - m), e1 = __expf(x1 - m), e2 = __expf(x2 - m);
            float e3 = (lane < 8) ? __expf(x3 - m) : 0.f;
            float ssum = e0 + e1 + e2 + e3;
            #pragma unroll
            for (int off = 32; off; off >>= 1) ssum += __shfl_xor(ssum, off, 64);
            float inv = 1.f / ssum;
            W4[lane * 4 + wv]         = e0 * inv;
            W4[(lane + 64) * 4 + wv]  = e1 * inv;
            W4[(lane + 128) * 4 + wv] = e2 * inv;
            if (lane < 8) W4[(lane + 192) * 4 + wv] = e3 * inv;
        }
        __syncthreads();

        // B: caps partials from register-resident hisP (exact ref summands)
        {
            float a0 = 0, a1 = 0, a2 = 0, a3 = 0;
            #pragma unroll
            for (int i = 0; i < 50; i++) {
                int l = wv * 50 + i;
                float4 w = *(const float4*)(W4 + l * 4);   // broadcast b128
                float  v = hp[i];
                a0 = fmaf(w.x, v, a0);
                a1 = fmaf(w.y, v, a1);
                a2 = fmaf(w.z, v, a2);
                a3 = fmaf(w.w, v, a3);
            }
            part[wv * 256 + lane]       = a0;
            part[wv * 256 + 64 + lane]  = a1;
            part[wv * 256 + 128 + lane] = a2;
            part[wv * 256 + 192 + lane] = a3;
        }
        __syncthreads();

        // C: reduce partials + squash; thread = (k = wv, d = lane)
        {
            float c = part[wv * 64 + lane]       + part[256 + wv * 64 + lane]
                    + part[512 + wv * 64 + lane] + part[768 + wv * 64 + lane];
            float n2 = c * c;
            #pragma unroll
            for (int off = 32; off; off >>= 1) n2 += __shfl_xor(n2, off, 64);
            float n  = sqrtf(n2);
            float sc = n2 / ((1.f + n2) * n + 1e-9f);
            c *= sc;
            caps4[lane * 4 + wv] = c;
        }
        __syncthreads();

        if (r < 2) {
            // D: B[k][l] += caps[k] . hisP[l]  (thread per l). hisP row
            // re-read from global P (L1/L2-hot). d ascending -> bit-identical.
            if (tid < LSEQ) {
                const float4* __restrict__ rowp = (const float4*)(P + idxs[tid] * 64);
                float d0 = 0, d1 = 0, d2 = 0, d3 = 0;
                #pragma unroll
                for (int j = 0; j < 16; j++) {
                    float4 v = rowp[j];
                    {
                        float4 c = *(const float4*)(caps4 + (j * 4 + 0) * 4);
                        d0 = fmaf(c.x, v.x, d0); d1 = fmaf(c.y, v.x, d1);
                        d2 = fmaf(c.z, v.x, d2); d3 = fmaf(c.w, v.x, d3);
                    }
                    {
                        float4 c = *(const float4*)(caps4 + (j * 4 + 1) * 4);
                        d0 = fmaf(c.x, v.y, d0); d1 = fmaf(c.y, v.y, d1);
                        d2 = fmaf(c.z, v.y, d2); d3 = fmaf(c.w, v.y, d3);
                    }
                    {
                        float4 c = *(const float4*)(caps4 + (j * 4 + 2) * 4);
                        d0 = fmaf(c.x, v.z, d0); d1 = fmaf(c.y, v.z, d1);
                        d2 = fmaf(c.z, v.z, d2); d3 = fmaf(c.w, v.z, d3);
                    }
                    {
                        float4 c = *(const float4*)(caps4 + (j * 4 + 3) * 4);
                        d0 = fmaf(c.x, v.w, d0); d1 = fmaf(c.y, v.w, d1);
                        d2 = fmaf(c.z, v.w, d2); d3 = fmaf(c.w, v.w, d3);
                    }
                }
                Bm[tid]       += d0;
                Bm[208 + tid] += d1;
                Bm[416 + tid] += d2;
                Bm[624 + tid] += d3;
            }
            __syncthreads();
        }
    }

    // MLP layer 1: h = relu(caps @ W1 + b1), h4[f*4+k]
    {
        const int f = tid;
        float h0 = 0, h1 = 0, h2 = 0, h3 = 0;
        #pragma unroll 8
        for (int d = 0; d < 64; d++) {
            float  w = W1[d * 256 + f];                      // coalesced, L2-hot
            float4 c = *(const float4*)(caps4 + d * 4);
            h0 = fmaf(c.x, w, h0);
            h1 = fmaf(c.y, w, h1);
            h2 = fmaf(c.z, w, h2);
            h3 = fmaf(c.w, w, h3);
        }
        float bb = b1[f];
        h0 = fmaxf(h0 + bb, 0.f);
        h1 = fmaxf(h1 + bb, 0.f);
        h2 = fmaxf(h2 + bb, 0.f);
        h3 = fmaxf(h3 + bb, 0.f);
        h4[f * 4 + 0] = h0; h4[f * 4 + 1] = h1;
        h4[f * 4 + 2] = h2; h4[f * 4 + 3] = h3;
    }
    __syncthreads();

    // MLP layer 2 partials: q = wv covers f in [q*64, q*64+64), d = lane
    {
        float o0 = 0, o1 = 0, o2 = 0, o3 = 0;
        #pragma unroll 8
        for (int i = 0; i < 64; i++) {
            int f = wv * 64 + i;
            float  w  = W2[f * 64 + lane];                   // coalesced, L2-hot
            float4 hv = *(const float4*)(h4 + f * 4);        // broadcast b128
            o0 = fmaf(hv.x, w, o0);
            o1 = fmaf(hv.y, w, o1);
            o2 = fmaf(hv.z, w, o2);
            o3 = fmaf(hv.w, w, o3);
        }
        part[wv * 256 + lane]       = o0;
        part[wv * 256 + 64 + lane]  = o1;
        part[wv * 256 + 128 + lane] = o2;
        part[wv * 256 + 192 + lane] = o3;
    }
    __syncthreads();
    {
        float o = part[wv * 64 + lane]       + part[256 + wv * 64 + lane]
                + part[512 + wv * 64 + lane] + part[768 + wv * 64 + lane];
        out[b * 256 + tid] = o + b2[lane];   // (b, k=wv, d=lane) contiguous
    }
}

extern "C" void kernel_launch(void* const* d_in, const int* in_sizes, int n_in,
                              void* d_out, int out_size, void* d_ws, size_t ws_size,
                              hipStream_t stream) {
    const int*   his = (const int*)  d_in[0];
    const float* E   = (const float*)d_in[1];
    const float* S   = (const float*)d_in[2];
    const float* B0  = (const float*)d_in[3];
    const float* W1  = (const float*)d_in[4];
    const float* b1  = (const float*)d_in[5];
    const float* W2  = (const float*)d_in[6];
    const float* b2  = (const float*)d_in[7];
    float* out = (float*)d_out;
    float* P   = (float*)d_ws;            // NVOC*64 floats = 25.6 MB scratch

    precompute_P<<<(NVOC + 63) / 64, 256, 0, stream>>>(E, S, P);
    mind_row<<<4096, 256, 0, stream>>>(his, P, B0, W1, b1, W2, b2, out);
}

// Round 8
// 253.420 us; speedup vs baseline: 1.2042x; 1.2042x over previous
//
#include <hip/hip_runtime.h>

#define LSEQ 200
#define KCAP 4
#define NVOC 100000

// ---------------------------------------------------------------------------
// Kernel 1: P = (E with row 0 zeroed) @ S, P: (NVOC, 64) in workspace.
// Verbatim round-6 version (passed; ~13 us). 64x64 tile, 4x4 per-thread.
// ---------------------------------------------------------------------------
__global__ __launch_bounds__(256) void precompute_P(
    const float* __restrict__ E, const float* __restrict__ S,
    float* __restrict__ P)
{
    __shared__ __align__(16) float Sl[64 * 64];   // Sl[e*64 + d]
    __shared__ __align__(16) float Et[64 * 68];   // Et[e*68 + r] = E[(vbase+r)*64+e]
    const int tid   = threadIdx.x;
    const int vbase = blockIdx.x * 64;

    #pragma unroll
    for (int t = tid; t < 4096; t += 256) Sl[t] = S[t];
    #pragma unroll
    for (int t = tid; t < 4096; t += 256) {
        int r = t >> 6, e = t & 63;               // wave: r fixed, e=lane -> coalesced
        int v = vbase + r;
        Et[e * 68 + r] = (v < NVOC) ? E[v * 64 + e] : 0.f;
    }
    __syncthreads();

    const int rq = tid >> 4;                      // 16 row-quads
    const int cq = tid & 15;                      // 16 col-quads
    float a00=0,a01=0,a02=0,a03=0, a10=0,a11=0,a12=0,a13=0;
    float a20=0,a21=0,a22=0,a23=0, a30=0,a31=0,a32=0,a33=0;
    #pragma unroll 8
    for (int e = 0; e < 64; e++) {
        float4 ev = *(const float4*)(Et + e * 68 + rq * 4);
        float4 sv = *(const float4*)(Sl + e * 64 + cq * 4);
        a00 = fmaf(ev.x, sv.x, a00); a01 = fmaf(ev.x, sv.y, a01);
        a02 = fmaf(ev.x, sv.z, a02); a03 = fmaf(ev.x, sv.w, a03);
        a10 = fmaf(ev.y, sv.x, a10); a11 = fmaf(ev.y, sv.y, a11);
        a12 = fmaf(ev.y, sv.z, a12); a13 = fmaf(ev.y, sv.w, a13);
        a20 = fmaf(ev.z, sv.x, a20); a21 = fmaf(ev.z, sv.y, a21);
        a22 = fmaf(ev.z, sv.z, a22); a23 = fmaf(ev.z, sv.w, a23);
        a30 = fmaf(ev.w, sv.x, a30); a31 = fmaf(ev.w, sv.y, a31);
        a32 = fmaf(ev.w, sv.z, a32); a33 = fmaf(ev.w, sv.w, a33);
    }

    const int r0 = vbase + rq * 4;
    float4 o0 = make_float4(a00, a01, a02, a03);
    float4 o1 = make_float4(a10, a11, a12, a13);
    float4 o2 = make_float4(a20, a21, a22, a23);
    float4 o3 = make_float4(a30, a31, a32, a33);
    if (r0 == 0) o0 = make_float4(0.f, 0.f, 0.f, 0.f);  // padding_idx=0
    if (r0 + 0 < NVOC) *(float4*)(P + (r0 + 0) * 64 + cq * 4) = o0;
    if (r0 + 1 < NVOC) *(float4*)(P + (r0 + 1) * 64 + cq * 4) = o1;
    if (r0 + 2 < NVOC) *(float4*)(P + (r0 + 2) * 64 + cq * 4) = o2;
    if (r0 + 3 < NVOC) *(float4*)(P + (r0 + 3) * 64 + cq * 4) = o3;
}

// ---------------------------------------------------------------------------
// Kernel 2: one batch row per block, 512 threads = 8 waves.
// Rationale (r7 post-mortem): gfx950 residency levels are coarse (<=64 VGPR
// -> 32 waves/CU, <=128 -> 16). hp[50] can't fit 64 -> r7 spilled (VGPR 32,
// 205 MB scratch). 8-wave blocks give hp[25] (~40 VGPR) -> 32-wave level
// reachable WITHOUT spill. Same total work, 2x resident waves.
//   A (softmax) / C (squash): waves 0-3 only (short phases), code verbatim.
//   B: 8 x 25-l chunks (association change, expected same error scale).
//   D: verbatim (tid<200).
//   MLP1: thread pair per f (2 capsule-chains each; per-output chain
//   unchanged). MLP2: 8 x 32-f partials.
// Spill canaries: VGPR_Count ~32, or WRITE_SIZE >> 4 MB.
//
// LDS pool (floats), 21440 B -> 4 blocks/CU = 32 waves/CU:
//   Bm    [0    .. 832)   [k*208 + l]
//   W4    [832  .. 1632)  [l*4 + k]   (16B-aligned float4 reads)
//   caps4 [1632 .. 1888)  [d*4 + k]   (16B-aligned)
//   bigneg[1888 .. 2088)
//   idxs  [2088 .. 2288)  int[200], live through phase D
//   SC    [2288 .. 5360)  part[8*256] | h4 = SC+2048 (disjoint from part)
// ---------------------------------------------------------------------------
__global__ __launch_bounds__(512, 8) void mind_row(
    const int*   __restrict__ his, const float* __restrict__ P,
    const float* __restrict__ B0,  const float* __restrict__ W1,
    const float* __restrict__ b1,  const float* __restrict__ W2,
    const float* __restrict__ b2,  float* __restrict__ out)
{
    __shared__ __align__(16) float POOL[5360];
    float* Bm     = POOL;          // [k*208 + l]
    float* W4     = POOL + 832;    // [l*4 + k]
    float* caps4  = POOL + 1632;   // [d*4 + k]
    float* bigneg = POOL + 1888;   // [200]
    int*   idxs   = (int*)(POOL + 2088);   // [200]
    float* SC     = POOL + 2288;   // 3072-float region
    float* part   = SC;            // [q*256 + k*64 + d], q = 0..7
    float* h4     = SC + 2048;     // [f*4 + k]

    const int b    = blockIdx.x;
    const int tid  = threadIdx.x;
    const int lane = tid & 63;
    const int wv   = tid >> 6;     // 0..7

    // ---- setup -------------------------------------------------------------
    if (tid < LSEQ) {
        int id = his[b * LSEQ + tid];
        idxs[tid]   = id;
        bigneg[tid] = (id != 0) ? 0.f : -1e30f;
        #pragma unroll
        for (int k = 0; k < KCAP; k++) Bm[k * 208 + tid] = B0[k * LSEQ + tid];
    }
    __syncthreads();

    // ---- gather hisP rows: wave covers l in [wv*25, wv*25+25), lane = d ----
    float hp[25];
    #pragma unroll
    for (int i = 0; i < 25; i++) {
        int l = wv * 25 + i;
        hp[i] = P[idxs[l] * 64 + lane];     // 256B coalesced per wave; row0=0
    }

    for (int r = 0; r < 3; r++) {
        // A: masked softmax over l, capsule k = wv; waves 0-3 only (verbatim)
        if (wv < KCAP) {
            const float* Bk = Bm + wv * 208;
            float x0 = Bk[lane]       + bigneg[lane];
            float x1 = Bk[lane + 64]  + bigneg[lane + 64];
            float x2 = Bk[lane + 128] + bigneg[lane + 128];
            float x3 = (lane < 8) ? (Bk[lane + 192] + bigneg[lane + 192]) : -3.0e38f;
            float m = fmaxf(fmaxf(x0, x1), fmaxf(x2, x3));
            #pragma unroll
            for (int off = 32; off; off >>= 1) m = fmaxf(m, __shfl_xor(m, off, 64));
            float e0 = __expf(x0 - m), e1 = __expf(x1 - m), e2 = __expf(x2 - m);
            float e3 = (lane < 8) ? __expf(x3 - m) : 0.f;
            float ssum = e0 + e1 + e2 + e3;
            #pragma unroll
            for (int off = 32; off; off >>= 1) ssum += __shfl_xor(ssum, off, 64);
            float inv = 1.f / ssum;
            W4[lane * 4 + wv]         = e0 * inv;
            W4[(lane + 64) * 4 + wv]  = e1 * inv;
            W4[(lane + 128) * 4 + wv] = e2 * inv;
            if (lane < 8) W4[(lane + 192) * 4 + wv] = e3 * inv;
        }
        __syncthreads();

        // B: caps partials from register-resident hisP (8 waves x 25 l's)
        {
            float a0 = 0, a1 = 0, a2 = 0, a3 = 0;
            #pragma unroll
            for (int i = 0; i < 25; i++) {
                int l = wv * 25 + i;
                float4 w = *(const float4*)(W4 + l * 4);   // broadcast b128
                float  v = hp[i];
                a0 = fmaf(w.x, v, a0);
                a1 = fmaf(w.y, v, a1);
                a2 = fmaf(w.z, v, a2);
                a3 = fmaf(w.w, v, a3);
            }
            part[wv * 256 + lane]       = a0;
            part[wv * 256 + 64 + lane]  = a1;
            part[wv * 256 + 128 + lane] = a2;
            part[wv * 256 + 192 + lane] = a3;
        }
        __syncthreads();

        // C: reduce 8 partials (ascending q) + squash; thread = (k=wv, d=lane)
        if (wv < KCAP) {
            float c = part[wv * 64 + lane];
            #pragma unroll
            for (int q = 1; q < 8; q++) c += part[q * 256 + wv * 64 + lane];
            float n2 = c * c;
            #pragma unroll
            for (int off = 32; off; off >>= 1) n2 += __shfl_xor(n2, off, 64);
            float n  = sqrtf(n2);
            float sc = n2 / ((1.f + n2) * n + 1e-9f);
            c *= sc;
            caps4[lane * 4 + wv] = c;
        }
        __syncthreads();

        if (r < 2) {
            // D: B[k][l] += caps[k] . hisP[l]  (thread per l; verbatim).
            // hisP row re-read from global P (L1/L2-hot), d ascending.
            if (tid < LSEQ) {
                const float4* __restrict__ rowp = (const float4*)(P + idxs[tid] * 64);
                float d0 = 0, d1 = 0, d2 = 0, d3 = 0;
                #pragma unroll
                for (int j = 0; j < 16; j++) {
                    float4 v = rowp[j];
                    {
                        float4 c = *(const float4*)(caps4 + (j * 4 + 0) * 4);
                        d0 = fmaf(c.x, v.x, d0); d1 = fmaf(c.y, v.x, d1);
                        d2 = fmaf(c.z, v.x, d2); d3 = fmaf(c.w, v.x, d3);
                    }
                    {
                        float4 c = *(const float4*)(caps4 + (j * 4 + 1) * 4);
                        d0 = fmaf(c.x, v.y, d0); d1 = fmaf(c.y, v.y, d1);
                        d2 = fmaf(c.z, v.y, d2); d3 = fmaf(c.w, v.y, d3);
                    }
                    {
                        float4 c = *(const float4*)(caps4 + (j * 4 + 2) * 4);
                        d0 = fmaf(c.x, v.z, d0); d1 = fmaf(c.y, v.z, d1);
                        d2 = fmaf(c.z, v.z, d2); d3 = fmaf(c.w, v.z, d3);
                    }
                    {
                        float4 c = *(const float4*)(caps4 + (j * 4 + 3) * 4);
                        d0 = fmaf(c.x, v.w, d0); d1 = fmaf(c.y, v.w, d1);
                        d2 = fmaf(c.z, v.w, d2); d3 = fmaf(c.w, v.w, d3);
                    }
                }
                Bm[tid]       += d0;
                Bm[208 + tid] += d1;
                Bm[416 + tid] += d2;
                Bm[624 + tid] += d3;
            }
            __syncthreads();
        }
    }

    // MLP layer 1: thread pair per f; each thread owns 2 capsule-chains.
    // Per-(f,k) fmaf chain over d ascending: identical to previous rounds.
    {
        const int f  = tid >> 1;
        const int kb = (tid & 1) * 2;
        float h0 = 0, h1 = 0;
        #pragma unroll 8
        for (int d = 0; d < 64; d++) {
            float  w = W1[d * 256 + f];                      // L2-hot
            float2 c = *(const float2*)(caps4 + d * 4 + kb); // 8B-aligned
            h0 = fmaf(c.x, w, h0);
            h1 = fmaf(c.y, w, h1);
        }
        float bb = b1[f];
        h0 = fmaxf(h0 + bb, 0.f);
        h1 = fmaxf(h1 + bb, 0.f);
        *(float2*)(h4 + f * 4 + kb) = make_float2(h0, h1);
    }
    __syncthreads();

    // MLP layer 2 partials: wave q covers f in [q*32, q*32+32), d = lane
    {
        float o0 = 0, o1 = 0, o2 = 0, o3 = 0;
        #pragma unroll 8
        for (int i = 0; i < 32; i++) {
            int f = wv * 32 + i;
            float  w  = W2[f * 64 + lane];                   // L2-hot
            float4 hv = *(const float4*)(h4 + f * 4);        // broadcast b128
            o0 = fmaf(hv.x, w, o0);
            o1 = fmaf(hv.y, w, o1);
            o2 = fmaf(hv.z, w, o2);
            o3 = fmaf(hv.w, w, o3);
        }
        part[wv * 256 + lane]       = o0;
        part[wv * 256 + 64 + lane]  = o1;
        part[wv * 256 + 128 + lane] = o2;
        part[wv * 256 + 192 + lane] = o3;
    }
    __syncthreads();
    if (tid < 256) {
        float o = part[tid];
        #pragma unroll
        for (int q = 1; q < 8; q++) o += part[q * 256 + tid];
        out[b * 256 + tid] = o + b2[tid & 63];   // (b, k, d) contiguous
    }
}

extern "C" void kernel_launch(void* const* d_in, const int* in_sizes, int n_in,
                              void* d_out, int out_size, void* d_ws, size_t ws_size,
                              hipStream_t stream) {
    const int*   his = (const int*)  d_in[0];
    const float* E   = (const float*)d_in[1];
    const float* S   = (const float*)d_in[2];
    const float* B0  = (const float*)d_in[3];
    const float* W1  = (const float*)d_in[4];
    const float* b1  = (const float*)d_in[5];
    const float* W2  = (const float*)d_in[6];
    const float* b2  = (const float*)d_in[7];
    float* out = (float*)d_out;
    float* P   = (float*)d_ws;            // NVOC*64 floats = 25.6 MB scratch

    precompute_P<<<(NVOC + 63) / 64, 256, 0, stream>>>(E, S, P);
    mind_row<<<4096, 512, 0, stream>>>(his, P, B0, W1, b1, W2, b2, out);
}

// Round 9
// 229.738 us; speedup vs baseline: 1.3283x; 1.1031x over previous
//
#include <hip/hip_runtime.h>

#define LSEQ 200
#define KCAP 4
#define NVOC 100000

// ---------------------------------------------------------------------------
// Kernel 1: P = (E with row 0 zeroed) @ S, P: (NVOC, 64) in workspace.
// Verbatim round-6 version (passed; ~13 us). 64x64 tile, 4x4 per-thread.
// ---------------------------------------------------------------------------
__global__ __launch_bounds__(256) void precompute_P(
    const float* __restrict__ E, const float* __restrict__ S,
    float* __restrict__ P)
{
    __shared__ __align__(16) float Sl[64 * 64];   // Sl[e*64 + d]
    __shared__ __align__(16) float Et[64 * 68];   // Et[e*68 + r] = E[(vbase+r)*64+e]
    const int tid   = threadIdx.x;
    const int vbase = blockIdx.x * 64;

    #pragma unroll
    for (int t = tid; t < 4096; t += 256) Sl[t] = S[t];
    #pragma unroll
    for (int t = tid; t < 4096; t += 256) {
        int r = t >> 6, e = t & 63;               // wave: r fixed, e=lane -> coalesced
        int v = vbase + r;
        Et[e * 68 + r] = (v < NVOC) ? E[v * 64 + e] : 0.f;
    }
    __syncthreads();

    const int rq = tid >> 4;                      // 16 row-quads
    const int cq = tid & 15;                      // 16 col-quads
    float a00=0,a01=0,a02=0,a03=0, a10=0,a11=0,a12=0,a13=0;
    float a20=0,a21=0,a22=0,a23=0, a30=0,a31=0,a32=0,a33=0;
    #pragma unroll 8
    for (int e = 0; e < 64; e++) {
        float4 ev = *(const float4*)(Et + e * 68 + rq * 4);
        float4 sv = *(const float4*)(Sl + e * 64 + cq * 4);
        a00 = fmaf(ev.x, sv.x, a00); a01 = fmaf(ev.x, sv.y, a01);
        a02 = fmaf(ev.x, sv.z, a02); a03 = fmaf(ev.x, sv.w, a03);
        a10 = fmaf(ev.y, sv.x, a10); a11 = fmaf(ev.y, sv.y, a11);
        a12 = fmaf(ev.y, sv.z, a12); a13 = fmaf(ev.y, sv.w, a13);
        a20 = fmaf(ev.z, sv.x, a20); a21 = fmaf(ev.z, sv.y, a21);
        a22 = fmaf(ev.z, sv.z, a22); a23 = fmaf(ev.z, sv.w, a23);
        a30 = fmaf(ev.w, sv.x, a30); a31 = fmaf(ev.w, sv.y, a31);
        a32 = fmaf(ev.w, sv.z, a32); a33 = fmaf(ev.w, sv.w, a33);
    }

    const int r0 = vbase + rq * 4;
    float4 o0 = make_float4(a00, a01, a02, a03);
    float4 o1 = make_float4(a10, a11, a12, a13);
    float4 o2 = make_float4(a20, a21, a22, a23);
    float4 o3 = make_float4(a30, a31, a32, a33);
    if (r0 == 0) o0 = make_float4(0.f, 0.f, 0.f, 0.f);  // padding_idx=0
    if (r0 + 0 < NVOC) *(float4*)(P + (r0 + 0) * 64 + cq * 4) = o0;
    if (r0 + 1 < NVOC) *(float4*)(P + (r0 + 1) * 64 + cq * 4) = o1;
    if (r0 + 2 < NVOC) *(float4*)(P + (r0 + 2) * 64 + cq * 4) = o2;
    if (r0 + 3 < NVOC) *(float4*)(P + (r0 + 3) * 64 + cq * 4) = o3;
}

// ---------------------------------------------------------------------------
// Kernel 2: one batch row per block, 512 threads = 8 waves.
// Arithmetic VERBATIM from passing round 8 (absmax 4.88e-4).
// ONE change: __launch_bounds__(512,8) -> __launch_bounds__(512) +
// amdgpu_waves_per_eu(6,8). Evidence across r0/1/5/6/7/8: the launch_bounds
// 2nd arg PINS waves/EU (occ tracks arg/8) and at 8 it imposes a 64-VGPR
// ceiling the allocator answers with a catastrophic spill to 32 VGPR
// (WRITE_SIZE 123-205 MB). waves_per_eu(6,8) gives an ~85-VGPR budget
// (hp[25]+overhead ~45-56 fits with no spill) while letting the HW reach
// 8 waves/EU = 32 waves/CU when the allocation lands <=64.
// Spill canaries: VGPR_Count <= 40, or WRITE_SIZE >> 4 MB.
//
// LDS pool (floats), 21440 B (4 blocks/CU @ 32 waves = 86 KB < 160 KB):
//   Bm    [0    .. 832)   [k*208 + l]
//   W4    [832  .. 1632)  [l*4 + k]
//   caps4 [1632 .. 1888)  [d*4 + k]
//   bigneg[1888 .. 2088)
//   idxs  [2088 .. 2288)  int[200]
//   SC    [2288 .. 5360)  part[8*256] | h4 = SC+2048
// ---------------------------------------------------------------------------
__global__ __launch_bounds__(512)
__attribute__((amdgpu_waves_per_eu(6, 8)))
void mind_row(
    const int*   __restrict__ his, const float* __restrict__ P,
    const float* __restrict__ B0,  const float* __restrict__ W1,
    const float* __restrict__ b1,  const float* __restrict__ W2,
    const float* __restrict__ b2,  float* __restrict__ out)
{
    __shared__ __align__(16) float POOL[5360];
    float* Bm     = POOL;          // [k*208 + l]
    float* W4     = POOL + 832;    // [l*4 + k]
    float* caps4  = POOL + 1632;   // [d*4 + k]
    float* bigneg = POOL + 1888;   // [200]
    int*   idxs   = (int*)(POOL + 2088);   // [200]
    float* SC     = POOL + 2288;   // 3072-float region
    float* part   = SC;            // [q*256 + k*64 + d], q = 0..7
    float* h4     = SC + 2048;     // [f*4 + k]

    const int b    = blockIdx.x;
    const int tid  = threadIdx.x;
    const int lane = tid & 63;
    const int wv   = tid >> 6;     // 0..7

    // ---- setup -------------------------------------------------------------
    if (tid < LSEQ) {
        int id = his[b * LSEQ + tid];
        idxs[tid]   = id;
        bigneg[tid] = (id != 0) ? 0.f : -1e30f;
        #pragma unroll
        for (int k = 0; k < KCAP; k++) Bm[k * 208 + tid] = B0[k * LSEQ + tid];
    }
    __syncthreads();

    // ---- gather hisP rows: wave covers l in [wv*25, wv*25+25), lane = d ----
    float hp[25];
    #pragma unroll
    for (int i = 0; i < 25; i++) {
        int l = wv * 25 + i;
        hp[i] = P[idxs[l] * 64 + lane];     // 256B coalesced per wave; row0=0
    }

    for (int r = 0; r < 3; r++) {
        // A: masked softmax over l, capsule k = wv; waves 0-3 only (verbatim)
        if (wv < KCAP) {
            const float* Bk = Bm + wv * 208;
            float x0 = Bk[lane]       + bigneg[lane];
            float x1 = Bk[lane + 64]  + bigneg[lane + 64];
            float x2 = Bk[lane + 128] + bigneg[lane + 128];
            float x3 = (lane < 8) ? (Bk[lane + 192] + bigneg[lane + 192]) : -3.0e38f;
            float m = fmaxf(fmaxf(x0, x1), fmaxf(x2, x3));
            #pragma unroll
            for (int off = 32; off; off >>= 1) m = fmaxf(m, __shfl_xor(m, off, 64));
            float e0 = __expf(x0 - m), e1 = __expf(x1 - m), e2 = __expf(x2 - m);
            float e3 = (lane < 8) ? __expf(x3 - m) : 0.f;
            float ssum = e0 + e1 + e2 + e3;
            #pragma unroll
            for (int off = 32; off; off >>= 1) ssum += __shfl_xor(ssum, off, 64);
            float inv = 1.f / ssum;
            W4[lane * 4 + wv]         = e0 * inv;
            W4[(lane + 64) * 4 + wv]  = e1 * inv;
            W4[(lane + 128) * 4 + wv] = e2 * inv;
            if (lane < 8) W4[(lane + 192) * 4 + wv] = e3 * inv;
        }
        __syncthreads();

        // B: caps partials from register-resident hisP (8 waves x 25 l's)
        {
            float a0 = 0, a1 = 0, a2 = 0, a3 = 0;
            #pragma unroll
            for (int i = 0; i < 25; i++) {
                int l = wv * 25 + i;
                float4 w = *(const float4*)(W4 + l * 4);   // broadcast b128
                float  v = hp[i];
                a0 = fmaf(w.x, v, a0);
                a1 = fmaf(w.y, v, a1);
                a2 = fmaf(w.z, v, a2);
                a3 = fmaf(w.w, v, a3);
            }
            part[wv * 256 + lane]       = a0;
            part[wv * 256 + 64 + lane]  = a1;
            part[wv * 256 + 128 + lane] = a2;
            part[wv * 256 + 192 + lane] = a3;
        }
        __syncthreads();

        // C: reduce 8 partials (ascending q) + squash; thread = (k=wv, d=lane)
        if (wv < KCAP) {
            float c = part[wv * 64 + lane];
            #pragma unroll
            for (int q = 1; q < 8; q++) c += part[q * 256 + wv * 64 + lane];
            float n2 = c * c;
            #pragma unroll
            for (int off = 32; off; off >>= 1) n2 += __shfl_xor(n2, off, 64);
            float n  = sqrtf(n2);
            float sc = n2 / ((1.f + n2) * n + 1e-9f);
            c *= sc;
            caps4[lane * 4 + wv] = c;
        }
        __syncthreads();

        if (r < 2) {
            // D: B[k][l] += caps[k] . hisP[l]  (thread per l; verbatim).
            // hisP row re-read from global P (L1/L2-hot), d ascending.
            if (tid < LSEQ) {
                const float4* __restrict__ rowp = (const float4*)(P + idxs[tid] * 64);
                float d0 = 0, d1 = 0, d2 = 0, d3 = 0;
                #pragma unroll
                for (int j = 0; j < 16; j++) {
                    float4 v = rowp[j];
                    {
                        float4 c = *(const float4*)(caps4 + (j * 4 + 0) * 4);
                        d0 = fmaf(c.x, v.x, d0); d1 = fmaf(c.y, v.x, d1);
                        d2 = fmaf(c.z, v.x, d2); d3 = fmaf(c.w, v.x, d3);
                    }
                    {
                        float4 c = *(const float4*)(caps4 + (j * 4 + 1) * 4);
                        d0 = fmaf(c.x, v.y, d0); d1 = fmaf(c.y, v.y, d1);
                        d2 = fmaf(c.z, v.y, d2); d3 = fmaf(c.w, v.y, d3);
                    }
                    {
                        float4 c = *(const float4*)(caps4 + (j * 4 + 2) * 4);
                        d0 = fmaf(c.x, v.z, d0); d1 = fmaf(c.y, v.z, d1);
                        d2 = fmaf(c.z, v.z, d2); d3 = fmaf(c.w, v.z, d3);
                    }
                    {
                        float4 c = *(const float4*)(caps4 + (j * 4 + 3) * 4);
                        d0 = fmaf(c.x, v.w, d0); d1 = fmaf(c.y, v.w, d1);
                        d2 = fmaf(c.z, v.w, d2); d3 = fmaf(c.w, v.w, d3);
                    }
                }
                Bm[tid]       += d0;
                Bm[208 + tid] += d1;
                Bm[416 + tid] += d2;
                Bm[624 + tid] += d3;
            }
            __syncthreads();
        }
    }

    // MLP layer 1: thread pair per f; each thread owns 2 capsule-chains.
    // Per-(f,k) fmaf chain over d ascending: identical to previous rounds.
    {
        const int f  = tid >> 1;
        const int kb = (tid & 1) * 2;
        float h0 = 0, h1 = 0;
        #pragma unroll 8
        for (int d = 0; d < 64; d++) {
            float  w = W1[d * 256 + f];                      // L2-hot
            float2 c = *(const float2*)(caps4 + d * 4 + kb); // 8B-aligned
            h0 = fmaf(c.x, w, h0);
            h1 = fmaf(c.y, w, h1);
        }
        float bb = b1[f];
        h0 = fmaxf(h0 + bb, 0.f);
        h1 = fmaxf(h1 + bb, 0.f);
        *(float2*)(h4 + f * 4 + kb) = make_float2(h0, h1);
    }
    __syncthreads();

    // MLP layer 2 partials: wave q covers f in [q*32, q*32+32), d = lane
    {
        float o0 = 0, o1 = 0, o2 = 0, o3 = 0;
        #pragma unroll 8
        for (int i = 0; i < 32; i++) {
            int f = wv * 32 + i;
            float  w  = W2[f * 64 + lane];                   // L2-hot
            float4 hv = *(const float4*)(h4 + f * 4);        // broadcast b128
            o0 = fmaf(hv.x, w, o0);
            o1 = fmaf(hv.y, w, o1);
            o2 = fmaf(hv.z, w, o2);
            o3 = fmaf(hv.w, w, o3);
        }
        part[wv * 256 + lane]       = o0;
        part[wv * 256 + 64 + lane]  = o1;
        part[wv * 256 + 128 + lane] = o2;
        part[wv * 256 + 192 + lane] = o3;
    }
    __syncthreads();
    if (tid < 256) {
        float o = part[tid];
        #pragma unroll
        for (int q = 1; q < 8; q++) o += part[q * 256 + tid];
        out[b * 256 + tid] = o + b2[tid & 63];   // (b, k, d) contiguous
    }
}

extern "C" void kernel_launch(void* const* d_in, const int* in_sizes, int n_in,
                              void* d_out, int out_size, void* d_ws, size_t ws_size,
                              hipStream_t stream) {
    const int*   his = (const int*)  d_in[0];
    const float* E   = (const float*)d_in[1];
    const float* S   = (const float*)d_in[2];
    const float* B0  = (const float*)d_in[3];
    const float* W1  = (const float*)d_in[4];
    const float* b1  = (const float*)d_in[5];
    const float* W2  = (const float*)d_in[6];
    const float* b2  = (const float*)d_in[7];
    float* out = (float*)d_out;
    float* P   = (float*)d_ws;            // NVOC*64 floats = 25.6 MB scratch

    precompute_P<<<(NVOC + 63) / 64, 256, 0, stream>>>(E, S, P);
    mind_row<<<4096, 512, 0, stream>>>(his, P, B0, W1, b1, W2, b2, out);
}

// Round 10
// 221.919 us; speedup vs baseline: 1.3751x; 1.0352x over previous
//
#include <hip/hip_runtime.h>

#define LSEQ 200
#define KCAP 4
#define NVOC 100000

// ---------------------------------------------------------------------------
// Kernel 1: P = (E with row 0 zeroed) @ S, P: (NVOC, 64) in workspace.
// Verbatim round-6 version (passed; ~13 us). 64x64 tile, 4x4 per-thread.
// ---------------------------------------------------------------------------
__global__ __launch_bounds__(256) void precompute_P(
    const float* __restrict__ E, const float* __restrict__ S,
    float* __restrict__ P)
{
    __shared__ __align__(16) float Sl[64 * 64];   // Sl[e*64 + d]
    __shared__ __align__(16) float Et[64 * 68];   // Et[e*68 + r] = E[(vbase+r)*64+e]
    const int tid   = threadIdx.x;
    const int vbase = blockIdx.x * 64;

    #pragma unroll
    for (int t = tid; t < 4096; t += 256) Sl[t] = S[t];
    #pragma unroll
    for (int t = tid; t < 4096; t += 256) {
        int r = t >> 6, e = t & 63;               // wave: r fixed, e=lane -> coalesced
        int v = vbase + r;
        Et[e * 68 + r] = (v < NVOC) ? E[v * 64 + e] : 0.f;
    }
    __syncthreads();

    const int rq = tid >> 4;                      // 16 row-quads
    const int cq = tid & 15;                      // 16 col-quads
    float a00=0,a01=0,a02=0,a03=0, a10=0,a11=0,a12=0,a13=0;
    float a20=0,a21=0,a22=0,a23=0, a30=0,a31=0,a32=0,a33=0;
    #pragma unroll 8
    for (int e = 0; e < 64; e++) {
        float4 ev = *(const float4*)(Et + e * 68 + rq * 4);
        float4 sv = *(const float4*)(Sl + e * 64 + cq * 4);
        a00 = fmaf(ev.x, sv.x, a00); a01 = fmaf(ev.x, sv.y, a01);
        a02 = fmaf(ev.x, sv.z, a02); a03 = fmaf(ev.x, sv.w, a03);
        a10 = fmaf(ev.y, sv.x, a10); a11 = fmaf(ev.y, sv.y, a11);
        a12 = fmaf(ev.y, sv.z, a12); a13 = fmaf(ev.y, sv.w, a13);
        a20 = fmaf(ev.z, sv.x, a20); a21 = fmaf(ev.z, sv.y, a21);
        a22 = fmaf(ev.z, sv.z, a22); a23 = fmaf(ev.z, sv.w, a23);
        a30 = fmaf(ev.w, sv.x, a30); a31 = fmaf(ev.w, sv.y, a31);
        a32 = fmaf(ev.w, sv.z, a32); a33 = fmaf(ev.w, sv.w, a33);
    }

    const int r0 = vbase + rq * 4;
    float4 o0 = make_float4(a00, a01, a02, a03);
    float4 o1 = make_float4(a10, a11, a12, a13);
    float4 o2 = make_float4(a20, a21, a22, a23);
    float4 o3 = make_float4(a30, a31, a32, a33);
    if (r0 == 0) o0 = make_float4(0.f, 0.f, 0.f, 0.f);  // padding_idx=0
    if (r0 + 0 < NVOC) *(float4*)(P + (r0 + 0) * 64 + cq * 4) = o0;
    if (r0 + 1 < NVOC) *(float4*)(P + (r0 + 1) * 64 + cq * 4) = o1;
    if (r0 + 2 < NVOC) *(float4*)(P + (r0 + 2) * 64 + cq * 4) = o2;
    if (r0 + 3 < NVOC) *(float4*)(P + (r0 + 3) * 64 + cq * 4) = o3;
}

// ---------------------------------------------------------------------------
// Kernel 2: one batch row per block (256 threads = 4 waves).
// Arithmetic VERBATIM from passing rounds 5/6 (absmax 4.88e-4; r6 = 128.4 us,
// VGPR 56, occ 40%).
// ONE change vs r6: __launch_bounds__(256,4) -> __launch_bounds__(256) +
// amdgpu_waves_per_eu(4,8).
// Evidence: r0/1/5/6 show the launch_bounds 2nd arg PINS occupancy at arg/8
// of max even when resources allow more (r6: VGPR 56 <= 64, LDS 17.4 KB ->
// 8 blocks/CU feasible, yet occ 40%). r9 validated waves_per_eu as the
// unpinning mechanism (no spill, occ floated up). min=4 keeps the allocator
// budget at 128 VGPR — identical to r6 — so codegen should reproduce the
// 56-VGPR allocation; the HW can then schedule up to 8 blocks/CU.
// Canaries: VGPR != 56 (codegen shifted), VGPR<=40 + WRITE >> 4 MB (spill).
//
// LDS pool 17344 B; 8 blocks/CU = 139 KB < 160 KB:
//   Bm    [0    .. 832)   [k*208 + l]
//   W4    [832  .. 1632)  [l*4 + k]
//   caps4 [1632 .. 1888)  [d*4 + k]
//   bigneg[1888 .. 2088)
//   idxs  [2088 .. 2288)  int[200], live whole kernel
//   SC    [2288 .. 4336)  union: part[1024] | h4 = SC+1024
// ---------------------------------------------------------------------------
__global__ __launch_bounds__(256)
__attribute__((amdgpu_waves_per_eu(4, 8)))
void mind_row(
    const int*   __restrict__ his, const float* __restrict__ P,
    const float* __restrict__ B0,  const float* __restrict__ W1,
    const float* __restrict__ b1,  const float* __restrict__ W2,
    const float* __restrict__ b2,  float* __restrict__ out)
{
    __shared__ __align__(16) float POOL[4336];
    float* Bm     = POOL;          // [k*208 + l]
    float* W4     = POOL + 832;    // [l*4 + k]
    float* caps4  = POOL + 1632;   // [d*4 + k]
    float* bigneg = POOL + 1888;   // [200]
    int*   idxs   = (int*)(POOL + 2088);   // [200], live whole kernel
    float* SC     = POOL + 2288;   // 2048-float union
    float* part   = SC;            // [q*256 + k*64 + d]  (phase B -> C; MLP2)
    float* h4     = SC + 1024;     // [f*4 + k]           (MLP)

    const int b    = blockIdx.x;
    const int tid  = threadIdx.x;
    const int lane = tid & 63;
    const int wv   = tid >> 6;

    // ---- setup -------------------------------------------------------------
    for (int l = tid; l < LSEQ; l += 256) {
        int id = his[b * LSEQ + l];
        idxs[l]   = id;
        bigneg[l] = (id != 0) ? 0.f : -1e30f;
    }
    if (tid < LSEQ) {
        #pragma unroll
        for (int k = 0; k < KCAP; k++) Bm[k * 208 + tid] = B0[k * LSEQ + tid];
    }
    __syncthreads();

    // ---- gather hisP rows: wave covers l in [wv*50, wv*50+50), lane = d ----
    float hp[50];
    #pragma unroll
    for (int i = 0; i < 50; i++) {
        int l = wv * 50 + i;
        hp[i] = P[idxs[l] * 64 + lane];     // 256B coalesced per wave; row0=0
    }

    for (int r = 0; r < 3; r++) {
        // A: masked softmax over l, capsule k = wv (one wave per capsule)
        {
            const float* Bk = Bm + wv * 208;
            float x0 = Bk[lane]       + bigneg[lane];
            float x1 = Bk[lane + 64]  + bigneg[lane + 64];
            float x2 = Bk[lane + 128] + bigneg[lane + 128];
            float x3 = (lane < 8) ? (Bk[lane + 192] + bigneg[lane + 192]) : -3.0e38f;
            float m = fmaxf(fmaxf(x0, x1), fmaxf(x2, x3));
            #pragma unroll
            for (int off = 32; off; off >>= 1) m = fmaxf(m, __shfl_xor(m, off, 64));
            float e0 = __expf(x0 - m), e1 = __expf(x1 - m), e2 = __expf(x2 - m);
            float e3 = (lane < 8) ? __expf(x3 - m) : 0.f;
            float ssum = e0 + e1 + e2 + e3;
            #pragma unroll
            for (int off = 32; off; off >>= 1) ssum += __shfl_xor(ssum, off, 64);
            float inv = 1.f / ssum;
            W4[lane * 4 + wv]         = e0 * inv;
            W4[(lane + 64) * 4 + wv]  = e1 * inv;
            W4[(lane + 128) * 4 + wv] = e2 * inv;
            if (lane < 8) W4[(lane + 192) * 4 + wv] = e3 * inv;
        }
        __syncthreads();

        // B: caps partials from register-resident hisP (exact ref summands)
        {
            float a0 = 0, a1 = 0, a2 = 0, a3 = 0;
            #pragma unroll
            for (int i = 0; i < 50; i++) {
                int l = wv * 50 + i;
                float4 w = *(const float4*)(W4 + l * 4);   // broadcast b128
                float  v = hp[i];
                a0 = fmaf(w.x, v, a0);
                a1 = fmaf(w.y, v, a1);
                a2 = fmaf(w.z, v, a2);
                a3 = fmaf(w.w, v, a3);
            }
            part[wv * 256 + lane]       = a0;
            part[wv * 256 + 64 + lane]  = a1;
            part[wv * 256 + 128 + lane] = a2;
            part[wv * 256 + 192 + lane] = a3;
        }
        __syncthreads();

        // C: reduce partials + squash; thread = (k = wv, d = lane)
        {
            float c = part[wv * 64 + lane]       + part[256 + wv * 64 + lane]
                    + part[512 + wv * 64 + lane] + part[768 + wv * 64 + lane];
            float n2 = c * c;
            #pragma unroll
            for (int off = 32; off; off >>= 1) n2 += __shfl_xor(n2, off, 64);
            float n  = sqrtf(n2);
            float sc = n2 / ((1.f + n2) * n + 1e-9f);
            c *= sc;
            caps4[lane * 4 + wv] = c;
        }
        __syncthreads();

        if (r < 2) {
            // D: B[k][l] += caps[k] . hisP[l]  (thread per l). hisP row
            // re-read from global P (L1/L2-hot). d ascending -> bit-identical.
            if (tid < LSEQ) {
                const float4* __restrict__ rowp = (const float4*)(P + idxs[tid] * 64);
                float d0 = 0, d1 = 0, d2 = 0, d3 = 0;
                #pragma unroll
                for (int j = 0; j < 16; j++) {
                    float4 v = rowp[j];
                    {
                        float4 c = *(const float4*)(caps4 + (j * 4 + 0) * 4);
                        d0 = fmaf(c.x, v.x, d0); d1 = fmaf(c.y, v.x, d1);
                        d2 = fmaf(c.z, v.x, d2); d3 = fmaf(c.w, v.x, d3);
                    }
                    {
                        float4 c = *(const float4*)(caps4 + (j * 4 + 1) * 4);
                        d0 = fmaf(c.x, v.y, d0); d1 = fmaf(c.y, v.y, d1);
                        d2 = fmaf(c.z, v.y, d2); d3 = fmaf(c.w, v.y, d3);
                    }
                    {
                        float4 c = *(const float4*)(caps4 + (j * 4 + 2) * 4);
                        d0 = fmaf(c.x, v.z, d0); d1 = fmaf(c.y, v.z, d1);
                        d2 = fmaf(c.z, v.z, d2); d3 = fmaf(c.w, v.z, d3);
                    }
                    {
                        float4 c = *(const float4*)(caps4 + (j * 4 + 3) * 4);
                        d0 = fmaf(c.x, v.w, d0); d1 = fmaf(c.y, v.w, d1);
                        d2 = fmaf(c.z, v.w, d2); d3 = fmaf(c.w, v.w, d3);
                    }
                }
                Bm[tid]       += d0;
                Bm[208 + tid] += d1;
                Bm[416 + tid] += d2;
                Bm[624 + tid] += d3;
            }
            __syncthreads();
        }
    }

    // MLP layer 1: h = relu(caps @ W1 + b1), h4[f*4+k]
    {
        const int f = tid;
        float h0 = 0, h1 = 0, h2 = 0, h3 = 0;
        #pragma unroll 8
        for (int d = 0; d < 64; d++) {
            float  w = W1[d * 256 + f];                      // coalesced, L2-hot
            float4 c = *(const float4*)(caps4 + d * 4);
            h0 = fmaf(c.x, w, h0);
            h1 = fmaf(c.y, w, h1);
            h2 = fmaf(c.z, w, h2);
            h3 = fmaf(c.w, w, h3);
        }
        float bb = b1[f];
        h0 = fmaxf(h0 + bb, 0.f);
        h1 = fmaxf(h1 + bb, 0.f);
        h2 = fmaxf(h2 + bb, 0.f);
        h3 = fmaxf(h3 + bb, 0.f);
        h4[f * 4 + 0] = h0; h4[f * 4 + 1] = h1;
        h4[f * 4 + 2] = h2; h4[f * 4 + 3] = h3;
    }
    __syncthreads();

    // MLP layer 2 partials: q = wv covers f in [q*64, q*64+64), d = lane
    {
        float o0 = 0, o1 = 0, o2 = 0, o3 = 0;
        #pragma unroll 8
        for (int i = 0; i < 64; i++) {
            int f = wv * 64 + i;
            float  w  = W2[f * 64 + lane];                   // coalesced, L2-hot
            float4 hv = *(const float4*)(h4 + f * 4);        // broadcast b128
            o0 = fmaf(hv.x, w, o0);
            o1 = fmaf(hv.y, w, o1);
            o2 = fmaf(hv.z, w, o2);
            o3 = fmaf(hv.w, w, o3);
        }
        part[wv * 256 + lane]       = o0;
        part[wv * 256 + 64 + lane]  = o1;
        part[wv * 256 + 128 + lane] = o2;
        part[wv * 256 + 192 + lane] = o3;
    }
    __syncthreads();
    {
        float o = part[wv * 64 + lane]       + part[256 + wv * 64 + lane]
                + part[512 + wv * 64 + lane] + part[768 + wv * 64 + lane];
        out[b * 256 + tid] = o + b2[lane];   // (b, k=wv, d=lane) contiguous
    }
}

extern "C" void kernel_launch(void* const* d_in, const int* in_sizes, int n_in,
                              void* d_out, int out_size, void* d_ws, size_t ws_size,
                              hipStream_t stream) {
    const int*   his = (const int*)  d_in[0];
    const float* E   = (const float*)d_in[1];
    const float* S   = (const float*)d_in[2];
    const float* B0  = (const float*)d_in[3];
    const float* W1  = (const float*)d_in[4];
    const float* b1  = (const float*)d_in[5];
    const float* W2  = (const float*)d_in[6];
    const float* b2  = (const float*)d_in[7];
    float* out = (float*)d_out;
    float* P   = (float*)d_ws;            // NVOC*64 floats = 25.6 MB scratch

    precompute_P<<<(NVOC + 63) / 64, 256, 0, stream>>>(E, S, P);
    mind_row<<<4096, 256, 0, stream>>>(his, P, B0, W1, b1, W2, b2, out);
}